// Round 2
// baseline (1939.146 us; speedup 1.0000x reference)
//
#include <hip/hip_runtime.h>
#include <math.h>

#define DIM      512
#define KC       8192     // codes
#define NR       8192     // rows
#define BM       128      // rows per block
#define BN       128      // codes per tile
#define BK       32       // depth per stage
#define NT       4        // code tiles per block
#define CHUNK    (BN*NT)  // 512 codes per block
#define NXB      (KC/CHUNK) // 16 partials per row
#define LDP      40       // LDS plane row stride (bf16 elems) = 80 B, conflict-free
#define EPS      0.125f   // margin below which we re-score exactly

typedef __attribute__((ext_vector_type(8))) short bf16x8;
typedef __attribute__((ext_vector_type(4))) float f32x4;
typedef __attribute__((ext_vector_type(8))) unsigned short u16x8;

static __device__ __forceinline__ unsigned short f2bf(float f) {
    unsigned u = __builtin_bit_cast(unsigned, f);
    u = u + 0x7FFFu + ((u >> 16) & 1u);          // round-to-nearest-even
    return (unsigned short)(u >> 16);
}
static __device__ __forceinline__ float bf2f(unsigned short h) {
    unsigned u = ((unsigned)h) << 16;
    return __builtin_bit_cast(float, u);
}

// ---------------------------------------------------------------------------
// e_sq[k] = sum_d E[k][d]^2   (one wave per code row) — unchanged from R1.
// ---------------------------------------------------------------------------
__global__ void esq_kernel(const float* __restrict__ E, float* __restrict__ e_sq) {
    const int wave = threadIdx.x >> 6;
    const int lane = threadIdx.x & 63;
    const int row  = blockIdx.x * 4 + wave;
    const float4* p = reinterpret_cast<const float4*>(E + (size_t)row * DIM) + lane * 2;
    float4 a = p[0], b = p[1];
    float s = a.x * a.x + a.y * a.y + a.z * a.z + a.w * a.w
            + b.x * b.x + b.y * b.y + b.z * b.z + b.w * b.w;
    #pragma unroll
    for (int off = 32; off > 0; off >>= 1) s += __shfl_down(s, off, 64);
    if (lane == 0) e_sq[row] = s;
}

// ---------------------------------------------------------------------------
// Split-bf16 MFMA scorer: per block 128 rows x 512 codes, running per-row
// (best, second, idx) over its codes; partials to ws.
// ---------------------------------------------------------------------------
__global__ __launch_bounds__(256, 2)
void vq_mfma_kernel(const float* __restrict__ X, const float* __restrict__ E,
                    const float* __restrict__ e_sq,
                    float* __restrict__ pbest, float* __restrict__ psec,
                    int* __restrict__ pidx)
{
    __shared__ unsigned short Xh[BM * LDP], Xl[BM * LDP];
    __shared__ unsigned short Eh[BM * LDP], El[BM * LDP];
    __shared__ float reds1[BM][2], reds2[BM][2];
    __shared__ int   redi [BM][2];

    const int tid  = threadIdx.x;
    const int lane = tid & 63;
    const int w    = tid >> 6;
    const int wr   = w >> 1;          // wave row half (0/1)
    const int wc   = w & 1;           // wave col half (0/1)
    const int row0  = blockIdx.y * BM;
    const int cbase = blockIdx.x * CHUNK;

    const int sr = tid >> 1;          // staging row 0..127
    const int sh = (tid & 1) * 16;    // staging col half (elems)

    const int fr = lane & 15;         // fragment row-in-16
    const int fk = (lane >> 4) * 8;   // fragment k offset (elems)

    float s1[16], s2[16];
    int   i1[16];
    #pragma unroll
    for (int i = 0; i < 16; ++i) { s1[i] = -INFINITY; s2[i] = -INFINITY; i1[i] = 0; }

    for (int nt = 0; nt < NT; ++nt) {
        const int code0 = cbase + nt * BN;
        f32x4 acc[4][4];
        #pragma unroll
        for (int m = 0; m < 4; ++m)
            #pragma unroll
            for (int n = 0; n < 4; ++n)
                acc[m][n] = (f32x4){0.f, 0.f, 0.f, 0.f};

        for (int d0 = 0; d0 < DIM; d0 += BK) {
            // ---- stage: load 16 fp32 of X-row and E-row, split hi/lo bf16 ----
            {
                const float* xp = X + (size_t)(row0 + sr) * DIM + d0 + sh;
                const float* ep = E + (size_t)(code0 + sr) * DIM + d0 + sh;
                float xv[16], ev[16];
                #pragma unroll
                for (int q = 0; q < 4; ++q) {
                    *reinterpret_cast<float4*>(&xv[q * 4]) = *reinterpret_cast<const float4*>(xp + q * 4);
                    *reinterpret_cast<float4*>(&ev[q * 4]) = *reinterpret_cast<const float4*>(ep + q * 4);
                }
                u16x8 xh[2], xl[2], eh[2], el[2];
                #pragma unroll
                for (int i = 0; i < 16; ++i) {
                    unsigned short h = f2bf(xv[i]);
                    unsigned short l = f2bf(xv[i] - bf2f(h));
                    xh[i >> 3][i & 7] = h; xl[i >> 3][i & 7] = l;
                    h = f2bf(ev[i]);
                    l = f2bf(ev[i] - bf2f(h));
                    eh[i >> 3][i & 7] = h; el[i >> 3][i & 7] = l;
                }
                const int wb = sr * LDP + sh;
                *reinterpret_cast<u16x8*>(&Xh[wb])     = xh[0];
                *reinterpret_cast<u16x8*>(&Xh[wb + 8]) = xh[1];
                *reinterpret_cast<u16x8*>(&Xl[wb])     = xl[0];
                *reinterpret_cast<u16x8*>(&Xl[wb + 8]) = xl[1];
                *reinterpret_cast<u16x8*>(&Eh[wb])     = eh[0];
                *reinterpret_cast<u16x8*>(&Eh[wb + 8]) = eh[1];
                *reinterpret_cast<u16x8*>(&El[wb])     = el[0];
                *reinterpret_cast<u16x8*>(&El[wb + 8]) = el[1];
            }
            __syncthreads();

            // ---- compute: 48 MFMAs (hh + hl + lh) ----
            bf16x8 bhf[4], blf[4];
            const int bbase = (wc * 64 + fr) * LDP + fk;
            #pragma unroll
            for (int n = 0; n < 4; ++n) {
                bhf[n] = *reinterpret_cast<const bf16x8*>(&Eh[bbase + n * 16 * LDP]);
                blf[n] = *reinterpret_cast<const bf16x8*>(&El[bbase + n * 16 * LDP]);
            }
            const int abase = (wr * 64 + fr) * LDP + fk;
            #pragma unroll
            for (int m = 0; m < 4; ++m) {
                bf16x8 ahf = *reinterpret_cast<const bf16x8*>(&Xh[abase + m * 16 * LDP]);
                bf16x8 alf = *reinterpret_cast<const bf16x8*>(&Xl[abase + m * 16 * LDP]);
                #pragma unroll
                for (int n = 0; n < 4; ++n) {
                    acc[m][n] = __builtin_amdgcn_mfma_f32_16x16x32_bf16(ahf, bhf[n], acc[m][n], 0, 0, 0);
                    acc[m][n] = __builtin_amdgcn_mfma_f32_16x16x32_bf16(ahf, blf[n], acc[m][n], 0, 0, 0);
                    acc[m][n] = __builtin_amdgcn_mfma_f32_16x16x32_bf16(alf, bhf[n], acc[m][n], 0, 0, 0);
                }
            }
            __syncthreads();
        }

        // ---- fold this code tile into running (best, second, idx) ----
        #pragma unroll
        for (int n = 0; n < 4; ++n) {
            const int code = code0 + wc * 64 + n * 16 + fr;
            const float es = e_sq[code];
            #pragma unroll
            for (int m = 0; m < 4; ++m) {
                #pragma unroll
                for (int r = 0; r < 4; ++r) {
                    const float s = fmaf(2.0f, acc[m][n][r], -es);
                    const int slot = m * 4 + r;
                    if (s > s1[slot]) { s2[slot] = s1[slot]; s1[slot] = s; i1[slot] = code; }
                    else if (s > s2[slot]) { s2[slot] = s; }
                    else if (s == s1[slot]) { s2[slot] = s; }   // exact tie -> margin 0
                }
            }
        }
    }

    // ---- cross-lane reduce within each 16-lane col group ----
    #pragma unroll
    for (int slot = 0; slot < 16; ++slot) {
        #pragma unroll
        for (int mask = 1; mask < 16; mask <<= 1) {
            float t1 = __shfl_xor(s1[slot], mask, 64);
            float t2 = __shfl_xor(s2[slot], mask, 64);
            int   j1 = __shfl_xor(i1[slot], mask, 64);
            if (t1 > s1[slot]) { s2[slot] = fmaxf(s1[slot], t2); s1[slot] = t1; i1[slot] = j1; }
            else if (t1 == s1[slot]) { s2[slot] = fmaxf(s2[slot], fmaxf(t1, t2)); i1[slot] = min(i1[slot], j1); }
            else { s2[slot] = fmaxf(s2[slot], t1); }
        }
    }

    if ((lane & 15) == 0) {
        #pragma unroll
        for (int m = 0; m < 4; ++m)
            #pragma unroll
            for (int r = 0; r < 4; ++r) {
                const int row = wr * 64 + m * 16 + (lane >> 4) * 4 + r;
                reds1[row][wc] = s1[m * 4 + r];
                reds2[row][wc] = s2[m * 4 + r];
                redi [row][wc] = i1[m * 4 + r];
            }
    }
    __syncthreads();

    if (tid < BM) {
        float a1 = reds1[tid][0], a2 = reds2[tid][0]; int ai = redi[tid][0];
        const float b1 = reds1[tid][1], b2 = reds2[tid][1]; const int bi = redi[tid][1];
        if (b1 > a1)       { a2 = fmaxf(a1, b2); a1 = b1; ai = bi; }
        else if (b1 == a1) { a2 = fmaxf(a2, fmaxf(b1, b2)); ai = min(ai, bi); }
        else               { a2 = fmaxf(a2, b1); }
        const int row = row0 + tid;
        pbest[(size_t)row * NXB + blockIdx.x] = a1;
        psec [(size_t)row * NXB + blockIdx.x] = a2;
        pidx [(size_t)row * NXB + blockIdx.x] = ai;
    }
}

// ---------------------------------------------------------------------------
// Merge NXB partials per row; flag rows with small margin for exact rescore.
// ---------------------------------------------------------------------------
__global__ void reduce_kernel(const float* __restrict__ pbest, const float* __restrict__ psec,
                              const int* __restrict__ pidx,
                              int* __restrict__ final_idx, int* __restrict__ flags)
{
    const int row = blockIdx.x * 256 + threadIdx.x;
    float s1 = -INFINITY, s2 = -INFINITY; int i1 = 0;
    #pragma unroll
    for (int j = 0; j < NXB; ++j) {
        const float t1 = pbest[(size_t)row * NXB + j];
        const float t2 = psec [(size_t)row * NXB + j];
        const int   j1 = pidx [(size_t)row * NXB + j];
        if (t1 > s1)       { s2 = fmaxf(s1, t2); s1 = t1; i1 = j1; }
        else if (t1 == s1) { s2 = fmaxf(s2, fmaxf(t1, t2)); i1 = min(i1, j1); }
        else               { s2 = fmaxf(s2, t1); }
    }
    final_idx[row] = i1;
    flags[row] = (s1 - s2 < EPS) ? 1 : 0;
}

// ---------------------------------------------------------------------------
// Exact fp32 rescore for flagged rows (expected ~1% of rows).
// ---------------------------------------------------------------------------
__global__ __launch_bounds__(256)
void rescue_kernel(const float* __restrict__ X, const float* __restrict__ E,
                   const float* __restrict__ e_sq,
                   const int* __restrict__ flags, int* __restrict__ final_idx)
{
    const int row = blockIdx.x;
    if (!flags[row]) return;
    const int tid = threadIdx.x;
    __shared__ float xs[DIM];
    __shared__ float rbest[256];
    __shared__ int   ridx[256];
    for (int i = tid; i < DIM; i += 256) xs[i] = X[(size_t)row * DIM + i];
    __syncthreads();

    float b = -INFINITY; int bi = 0;
    for (int c = tid; c < KC; c += 256) {
        const float4* ep = reinterpret_cast<const float4*>(E + (size_t)c * DIM);
        float dot = 0.f;
        for (int k = 0; k < DIM / 4; ++k) {
            const float4 e4 = ep[k];
            dot = fmaf(xs[4 * k + 0], e4.x, dot);
            dot = fmaf(xs[4 * k + 1], e4.y, dot);
            dot = fmaf(xs[4 * k + 2], e4.z, dot);
            dot = fmaf(xs[4 * k + 3], e4.w, dot);
        }
        const float s = fmaf(2.f, dot, -e_sq[c]);
        if (s > b) { b = s; bi = c; }      // ascending c: strict > keeps first occurrence
    }
    rbest[tid] = b; ridx[tid] = bi;
    __syncthreads();
    for (int off = 128; off > 0; off >>= 1) {
        if (tid < off) {
            const float ob = rbest[tid + off]; const int oi = ridx[tid + off];
            if (ob > rbest[tid] || (ob == rbest[tid] && oi < ridx[tid])) { rbest[tid] = ob; ridx[tid] = oi; }
        }
        __syncthreads();
    }
    if (tid == 0) final_idx[row] = ridx[0];
}

// ---------------------------------------------------------------------------
// Write index output (as float) and gather the winning code row.
// ---------------------------------------------------------------------------
__global__ void gather_kernel(const int* __restrict__ final_idx, const float* __restrict__ E,
                              float* __restrict__ out_q, float* __restrict__ out_i)
{
    const int row = blockIdx.x;
    const int bi = final_idx[row];
    if (threadIdx.x == 0) out_i[row] = (float)bi;
    const float4* src = reinterpret_cast<const float4*>(E + (size_t)bi * DIM);
    float4* dst = reinterpret_cast<float4*>(out_q + (size_t)row * DIM);
    dst[threadIdx.x] = src[threadIdx.x];
}

// ---------------------------------------------------------------------------
extern "C" void kernel_launch(void* const* d_in, const int* in_sizes, int n_in,
                              void* d_out, int out_size, void* d_ws, size_t ws_size,
                              hipStream_t stream) {
    const float* X = (const float*)d_in[0];   // [8192, 512]
    const float* E = (const float*)d_in[1];   // [8192, 512]

    float* out_q = (float*)d_out;                         // [8192, 512]
    float* out_i = (float*)d_out + (size_t)NR * DIM;      // [8192]

    float* e_sq      = (float*)d_ws;                      // 8192
    float* pbest     = e_sq + KC;                         // 8192*16
    float* psec      = pbest + (size_t)NR * NXB;          // 8192*16
    int*   pidx      = (int*)(psec + (size_t)NR * NXB);   // 8192*16
    int*   final_idx = pidx + (size_t)NR * NXB;           // 8192
    int*   flags     = final_idx + NR;                    // 8192

    hipLaunchKernelGGL(esq_kernel, dim3(KC / 4), dim3(256), 0, stream, E, e_sq);

    hipLaunchKernelGGL(vq_mfma_kernel, dim3(NXB, NR / BM), dim3(256), 0, stream,
                       X, E, e_sq, pbest, psec, pidx);

    hipLaunchKernelGGL(reduce_kernel, dim3(NR / 256), dim3(256), 0, stream,
                       pbest, psec, pidx, final_idx, flags);

    hipLaunchKernelGGL(rescue_kernel, dim3(NR), dim3(256), 0, stream,
                       X, E, e_sq, flags, final_idx);

    hipLaunchKernelGGL(gather_kernel, dim3(NR), dim3(128), 0, stream,
                       final_idx, E, out_q, out_i);
}

// Round 3
// 428.618 us; speedup vs baseline: 4.5242x; 4.5242x over previous
//
#include <hip/hip_runtime.h>
#include <math.h>

#define DIM      512
#define KC       8192     // codes
#define NR       8192     // rows
#define BM       128      // rows per block
#define BN       128      // codes per tile
#define BK       32       // depth per stage
#define NT       4        // code tiles per block
#define CHUNK    (BN*NT)  // 512 codes per block
#define NXB      (KC/CHUNK) // 16 partials per row
#define LDP      40       // LDS plane row stride (bf16 elems) = 80 B, conflict-free
#define EPS      0.125f   // margin below which we re-score exactly
#define MAXF     1024     // max flagged rows the rescue grid covers
#define RCODES   512      // codes per rescue block (4 waves x 128)

typedef __attribute__((ext_vector_type(8))) short bf16x8;
typedef __attribute__((ext_vector_type(4))) float f32x4;
typedef __attribute__((ext_vector_type(8))) unsigned short u16x8;

static __device__ __forceinline__ unsigned short f2bf(float f) {
    unsigned u = __builtin_bit_cast(unsigned, f);
    u = u + 0x7FFFu + ((u >> 16) & 1u);          // round-to-nearest-even
    return (unsigned short)(u >> 16);
}
static __device__ __forceinline__ float bf2f(unsigned short h) {
    unsigned u = ((unsigned)h) << 16;
    return __builtin_bit_cast(float, u);
}

// ---------------------------------------------------------------------------
// e_sq[k] = sum_d E[k][d]^2 (one wave per code row). Also zeroes fcount.
// ---------------------------------------------------------------------------
__global__ void esq_kernel(const float* __restrict__ E, float* __restrict__ e_sq,
                           int* __restrict__ fcount) {
    if (blockIdx.x == 0 && threadIdx.x == 0) *fcount = 0;
    const int wave = threadIdx.x >> 6;
    const int lane = threadIdx.x & 63;
    const int row  = blockIdx.x * 4 + wave;
    const float4* p = reinterpret_cast<const float4*>(E + (size_t)row * DIM) + lane * 2;
    float4 a = p[0], b = p[1];
    float s = a.x * a.x + a.y * a.y + a.z * a.z + a.w * a.w
            + b.x * b.x + b.y * b.y + b.z * b.z + b.w * b.w;
    #pragma unroll
    for (int off = 32; off > 0; off >>= 1) s += __shfl_down(s, off, 64);
    if (lane == 0) e_sq[row] = s;
}

// ---------------------------------------------------------------------------
// Split-bf16 MFMA scorer: per block 128 rows x 512 codes, running per-row
// (best, second, idx) over its codes; partials to ws. (Unchanged from R2.)
// ---------------------------------------------------------------------------
__global__ __launch_bounds__(256, 2)
void vq_mfma_kernel(const float* __restrict__ X, const float* __restrict__ E,
                    const float* __restrict__ e_sq,
                    float* __restrict__ pbest, float* __restrict__ psec,
                    int* __restrict__ pidx)
{
    __shared__ unsigned short Xh[BM * LDP], Xl[BM * LDP];
    __shared__ unsigned short Eh[BM * LDP], El[BM * LDP];
    __shared__ float reds1[BM][2], reds2[BM][2];
    __shared__ int   redi [BM][2];

    const int tid  = threadIdx.x;
    const int lane = tid & 63;
    const int w    = tid >> 6;
    const int wr   = w >> 1;          // wave row half (0/1)
    const int wc   = w & 1;           // wave col half (0/1)
    const int row0  = blockIdx.y * BM;
    const int cbase = blockIdx.x * CHUNK;

    const int sr = tid >> 1;          // staging row 0..127
    const int sh = (tid & 1) * 16;    // staging col half (elems)

    const int fr = lane & 15;         // fragment row-in-16
    const int fk = (lane >> 4) * 8;   // fragment k offset (elems)

    float s1[16], s2[16];
    int   i1[16];
    #pragma unroll
    for (int i = 0; i < 16; ++i) { s1[i] = -INFINITY; s2[i] = -INFINITY; i1[i] = 0; }

    for (int nt = 0; nt < NT; ++nt) {
        const int code0 = cbase + nt * BN;
        f32x4 acc[4][4];
        #pragma unroll
        for (int m = 0; m < 4; ++m)
            #pragma unroll
            for (int n = 0; n < 4; ++n)
                acc[m][n] = (f32x4){0.f, 0.f, 0.f, 0.f};

        for (int d0 = 0; d0 < DIM; d0 += BK) {
            // ---- stage: load 16 fp32 of X-row and E-row, split hi/lo bf16 ----
            {
                const float* xp = X + (size_t)(row0 + sr) * DIM + d0 + sh;
                const float* ep = E + (size_t)(code0 + sr) * DIM + d0 + sh;
                float xv[16], ev[16];
                #pragma unroll
                for (int q = 0; q < 4; ++q) {
                    *reinterpret_cast<float4*>(&xv[q * 4]) = *reinterpret_cast<const float4*>(xp + q * 4);
                    *reinterpret_cast<float4*>(&ev[q * 4]) = *reinterpret_cast<const float4*>(ep + q * 4);
                }
                u16x8 xh[2], xl[2], eh[2], el[2];
                #pragma unroll
                for (int i = 0; i < 16; ++i) {
                    unsigned short h = f2bf(xv[i]);
                    unsigned short l = f2bf(xv[i] - bf2f(h));
                    xh[i >> 3][i & 7] = h; xl[i >> 3][i & 7] = l;
                    h = f2bf(ev[i]);
                    l = f2bf(ev[i] - bf2f(h));
                    eh[i >> 3][i & 7] = h; el[i >> 3][i & 7] = l;
                }
                const int wb = sr * LDP + sh;
                *reinterpret_cast<u16x8*>(&Xh[wb])     = xh[0];
                *reinterpret_cast<u16x8*>(&Xh[wb + 8]) = xh[1];
                *reinterpret_cast<u16x8*>(&Xl[wb])     = xl[0];
                *reinterpret_cast<u16x8*>(&Xl[wb + 8]) = xl[1];
                *reinterpret_cast<u16x8*>(&Eh[wb])     = eh[0];
                *reinterpret_cast<u16x8*>(&Eh[wb + 8]) = eh[1];
                *reinterpret_cast<u16x8*>(&El[wb])     = el[0];
                *reinterpret_cast<u16x8*>(&El[wb + 8]) = el[1];
            }
            __syncthreads();

            // ---- compute: 48 MFMAs (hh + hl + lh) ----
            bf16x8 bhf[4], blf[4];
            const int bbase = (wc * 64 + fr) * LDP + fk;
            #pragma unroll
            for (int n = 0; n < 4; ++n) {
                bhf[n] = *reinterpret_cast<const bf16x8*>(&Eh[bbase + n * 16 * LDP]);
                blf[n] = *reinterpret_cast<const bf16x8*>(&El[bbase + n * 16 * LDP]);
            }
            const int abase = (wr * 64 + fr) * LDP + fk;
            #pragma unroll
            for (int m = 0; m < 4; ++m) {
                bf16x8 ahf = *reinterpret_cast<const bf16x8*>(&Xh[abase + m * 16 * LDP]);
                bf16x8 alf = *reinterpret_cast<const bf16x8*>(&Xl[abase + m * 16 * LDP]);
                #pragma unroll
                for (int n = 0; n < 4; ++n) {
                    acc[m][n] = __builtin_amdgcn_mfma_f32_16x16x32_bf16(ahf, bhf[n], acc[m][n], 0, 0, 0);
                    acc[m][n] = __builtin_amdgcn_mfma_f32_16x16x32_bf16(ahf, blf[n], acc[m][n], 0, 0, 0);
                    acc[m][n] = __builtin_amdgcn_mfma_f32_16x16x32_bf16(alf, bhf[n], acc[m][n], 0, 0, 0);
                }
            }
            __syncthreads();
        }

        // ---- fold this code tile into running (best, second, idx) ----
        #pragma unroll
        for (int n = 0; n < 4; ++n) {
            const int code = code0 + wc * 64 + n * 16 + fr;
            const float es = e_sq[code];
            #pragma unroll
            for (int m = 0; m < 4; ++m) {
                #pragma unroll
                for (int r = 0; r < 4; ++r) {
                    const float s = fmaf(2.0f, acc[m][n][r], -es);
                    const int slot = m * 4 + r;
                    if (s > s1[slot]) { s2[slot] = s1[slot]; s1[slot] = s; i1[slot] = code; }
                    else if (s > s2[slot]) { s2[slot] = s; }
                    else if (s == s1[slot]) { s2[slot] = s; }   // exact tie -> margin 0
                }
            }
        }
    }

    // ---- cross-lane reduce within each 16-lane col group ----
    #pragma unroll
    for (int slot = 0; slot < 16; ++slot) {
        #pragma unroll
        for (int mask = 1; mask < 16; mask <<= 1) {
            float t1 = __shfl_xor(s1[slot], mask, 64);
            float t2 = __shfl_xor(s2[slot], mask, 64);
            int   j1 = __shfl_xor(i1[slot], mask, 64);
            if (t1 > s1[slot]) { s2[slot] = fmaxf(s1[slot], t2); s1[slot] = t1; i1[slot] = j1; }
            else if (t1 == s1[slot]) { s2[slot] = fmaxf(s2[slot], fmaxf(t1, t2)); i1[slot] = min(i1[slot], j1); }
            else { s2[slot] = fmaxf(s2[slot], t1); }
        }
    }

    if ((lane & 15) == 0) {
        #pragma unroll
        for (int m = 0; m < 4; ++m)
            #pragma unroll
            for (int r = 0; r < 4; ++r) {
                const int row = wr * 64 + m * 16 + (lane >> 4) * 4 + r;
                reds1[row][wc] = s1[m * 4 + r];
                reds2[row][wc] = s2[m * 4 + r];
                redi [row][wc] = i1[m * 4 + r];
            }
    }
    __syncthreads();

    if (tid < BM) {
        float a1 = reds1[tid][0], a2 = reds2[tid][0]; int ai = redi[tid][0];
        const float b1 = reds1[tid][1], b2 = reds2[tid][1]; const int bi = redi[tid][1];
        if (b1 > a1)       { a2 = fmaxf(a1, b2); a1 = b1; ai = bi; }
        else if (b1 == a1) { a2 = fmaxf(a2, fmaxf(b1, b2)); ai = min(ai, bi); }
        else               { a2 = fmaxf(a2, b1); }
        const int row = row0 + tid;
        pbest[(size_t)row * NXB + blockIdx.x] = a1;
        psec [(size_t)row * NXB + blockIdx.x] = a2;
        pidx [(size_t)row * NXB + blockIdx.x] = ai;
    }
}

// ---------------------------------------------------------------------------
// Merge NXB partials per row; compact rows with small margin into frow[].
// ---------------------------------------------------------------------------
__global__ void reduce_kernel(const float* __restrict__ pbest, const float* __restrict__ psec,
                              const int* __restrict__ pidx,
                              int* __restrict__ final_idx,
                              int* __restrict__ fcount, int* __restrict__ frow,
                              int* __restrict__ fslot)
{
    const int row = blockIdx.x * 256 + threadIdx.x;
    float s1 = -INFINITY, s2 = -INFINITY; int i1 = 0;
    #pragma unroll
    for (int j = 0; j < NXB; ++j) {
        const float t1 = pbest[(size_t)row * NXB + j];
        const float t2 = psec [(size_t)row * NXB + j];
        const int   j1 = pidx [(size_t)row * NXB + j];
        if (t1 > s1)       { s2 = fmaxf(s1, t2); s1 = t1; i1 = j1; }
        else if (t1 == s1) { s2 = fmaxf(s2, fmaxf(t1, t2)); i1 = min(i1, j1); }
        else               { s2 = fmaxf(s2, t1); }
    }
    final_idx[row] = i1;
    int slot = -1;
    if (s1 - s2 < EPS) {
        const int f = atomicAdd(fcount, 1);
        if (f < MAXF) { frow[f] = row; slot = f; }
    }
    fslot[row] = slot;
}

// ---------------------------------------------------------------------------
// Exact fp32 rescore, parallel: block (f, chunk) scans 512 codes for one
// flagged row. Wave per code-group; lanes split the 512 dims; coalesced.
// Writes one (best, idx) partial per wave: 64 partials per flagged row.
// ---------------------------------------------------------------------------
__global__ __launch_bounds__(256)
void rescue_kernel(const float* __restrict__ X, const float* __restrict__ E,
                   const float* __restrict__ e_sq,
                   const int* __restrict__ fcount, const int* __restrict__ frow,
                   float* __restrict__ rbest, int* __restrict__ ridx)
{
    const int f = blockIdx.x;
    const int nf = *fcount;
    if (f >= nf || f >= MAXF) return;
    const int row  = frow[f];
    const int lane = threadIdx.x & 63;
    const int w    = threadIdx.x >> 6;

    const float4* xp = reinterpret_cast<const float4*>(X + (size_t)row * DIM) + lane * 2;
    const float4 x0 = xp[0], x1 = xp[1];

    const int c0 = blockIdx.y * RCODES + w * (RCODES / 4);
    float best = -INFINITY; int bi = 0;
    for (int c = c0; c < c0 + RCODES / 4; ++c) {
        const float4* ep = reinterpret_cast<const float4*>(E + (size_t)c * DIM) + lane * 2;
        const float4 e0 = ep[0], e1 = ep[1];
        float dot = x0.x * e0.x;
        dot = fmaf(x0.y, e0.y, dot);
        dot = fmaf(x0.z, e0.z, dot);
        dot = fmaf(x0.w, e0.w, dot);
        dot = fmaf(x1.x, e1.x, dot);
        dot = fmaf(x1.y, e1.y, dot);
        dot = fmaf(x1.z, e1.z, dot);
        dot = fmaf(x1.w, e1.w, dot);
        #pragma unroll
        for (int mask = 1; mask < 64; mask <<= 1) dot += __shfl_xor(dot, mask, 64);
        const float s = fmaf(2.f, dot, -e_sq[c]);
        if (s > best) { best = s; bi = c; }    // ascending c: first occurrence wins
    }
    if (lane == 0) {
        const int p = f * 64 + blockIdx.y * 4 + w;
        rbest[p] = best; ridx[p] = bi;
    }
}

// ---------------------------------------------------------------------------
// Final index (rescued rows merge their 64 partials), write index + gather.
// ---------------------------------------------------------------------------
__global__ void gather_kernel(const int* __restrict__ final_idx,
                              const int* __restrict__ fslot,
                              const float* __restrict__ rbest, const int* __restrict__ ridx,
                              const float* __restrict__ E,
                              float* __restrict__ out_q, float* __restrict__ out_i)
{
    const int row = blockIdx.x;
    __shared__ int s_bi;
    if (threadIdx.x < 64) {
        const int slot = fslot[row];
        int bi;
        if (slot >= 0) {
            float b = rbest[slot * 64 + threadIdx.x];
            bi = ridx[slot * 64 + threadIdx.x];
            #pragma unroll
            for (int mask = 1; mask < 64; mask <<= 1) {
                const float ob = __shfl_xor(b, mask, 64);
                const int   oi = __shfl_xor(bi, mask, 64);
                if (ob > b || (ob == b && oi < bi)) { b = ob; bi = oi; }
            }
        } else {
            bi = final_idx[row];
        }
        if (threadIdx.x == 0) { s_bi = bi; out_i[row] = (float)bi; }
    }
    __syncthreads();
    const int bi = s_bi;
    const float4* src = reinterpret_cast<const float4*>(E + (size_t)bi * DIM);
    float4* dst = reinterpret_cast<float4*>(out_q + (size_t)row * DIM);
    dst[threadIdx.x] = src[threadIdx.x];
}

// ---------------------------------------------------------------------------
extern "C" void kernel_launch(void* const* d_in, const int* in_sizes, int n_in,
                              void* d_out, int out_size, void* d_ws, size_t ws_size,
                              hipStream_t stream) {
    const float* X = (const float*)d_in[0];   // [8192, 512]
    const float* E = (const float*)d_in[1];   // [8192, 512]

    float* out_q = (float*)d_out;                         // [8192, 512]
    float* out_i = (float*)d_out + (size_t)NR * DIM;      // [8192]

    float* e_sq      = (float*)d_ws;                      // 8192 f
    float* pbest     = e_sq + KC;                         // 8192*16 f
    float* psec      = pbest + (size_t)NR * NXB;          // 8192*16 f
    int*   pidx      = (int*)(psec + (size_t)NR * NXB);   // 8192*16 i
    int*   final_idx = pidx + (size_t)NR * NXB;           // 8192 i
    int*   fcount    = final_idx + NR;                    // 1 i
    int*   frow      = fcount + 1;                        // MAXF i
    int*   fslot     = frow + MAXF;                       // 8192 i
    float* rbest     = (float*)(fslot + NR);              // MAXF*64 f
    int*   ridx      = (int*)(rbest + MAXF * 64);         // MAXF*64 i

    hipLaunchKernelGGL(esq_kernel, dim3(KC / 4), dim3(256), 0, stream, E, e_sq, fcount);

    hipLaunchKernelGGL(vq_mfma_kernel, dim3(NXB, NR / BM), dim3(256), 0, stream,
                       X, E, e_sq, pbest, psec, pidx);

    hipLaunchKernelGGL(reduce_kernel, dim3(NR / 256), dim3(256), 0, stream,
                       pbest, psec, pidx, final_idx, fcount, frow, fslot);

    hipLaunchKernelGGL(rescue_kernel, dim3(MAXF, KC / RCODES), dim3(256), 0, stream,
                       X, E, e_sq, fcount, frow, rbest, ridx);

    hipLaunchKernelGGL(gather_kernel, dim3(NR), dim3(128), 0, stream,
                       final_idx, fslot, rbest, ridx, E, out_q, out_i);
}

// Round 4
// 253.475 us; speedup vs baseline: 7.6502x; 1.6910x over previous
//
#include <hip/hip_runtime.h>
#include <math.h>

#define DIM      512
#define KC       8192     // codes
#define NR       8192     // rows
#define BM       128      // rows per block
#define BN       128      // codes per tile
#define NT       4        // code tiles per block
#define CHUNK    (BN*NT)  // 512 codes per block
#define NXB      (KC/CHUNK) // 16 partials per row
#define KT       (DIM/32) // 16 k-tiles of 32
#define EPS      0.125f   // margin below which we re-score exactly (>=12 sigma of f16 error)
#define MAXF     1024     // max flagged rows the rescue grid covers
#define RCODES   512      // codes per rescue block (4 waves x 128)

typedef __attribute__((ext_vector_type(8))) _Float16 f16x8;
typedef __attribute__((ext_vector_type(4))) float f32x4;

// ---------------------------------------------------------------------------
// Pack: fp32 -> fp16 in fragment-tiled layout. Tile = 16 rows x 32 k, stored
// in MFMA lane order: lane = (row&15) + 16*kg holds elems k = kg*8..kg*8+7.
// One wave per 1 KB tile. grid = (tiles/4, 2): y=0 -> X, y=1 -> E.
// ---------------------------------------------------------------------------
__global__ void pack_kernel(const float* __restrict__ X, const float* __restrict__ E,
                            _Float16* __restrict__ Xp, _Float16* __restrict__ Ep) {
    const float* src = blockIdx.y ? E : X;
    _Float16* dst = blockIdx.y ? Ep : Xp;
    const int tile = blockIdx.x * 4 + (threadIdx.x >> 6);
    const int lane = threadIdx.x & 63;
    const int rt = tile / KT, kt = tile % KT;
    const int row = rt * 16 + (lane & 15);
    const int k   = kt * 32 + (lane >> 4) * 8;
    const float4* p = reinterpret_cast<const float4*>(src + (size_t)row * DIM + k);
    const float4 a = p[0], b = p[1];
    f16x8 o;
    o[0] = (_Float16)a.x; o[1] = (_Float16)a.y; o[2] = (_Float16)a.z; o[3] = (_Float16)a.w;
    o[4] = (_Float16)b.x; o[5] = (_Float16)b.y; o[6] = (_Float16)b.z; o[7] = (_Float16)b.w;
    *reinterpret_cast<f16x8*>(dst + (size_t)tile * 512 + lane * 8) = o;
}

// ---------------------------------------------------------------------------
// e_sq[k] = sum_d E[k][d]^2 (fp32 exact, one wave per code). Zeroes fcount.
// ---------------------------------------------------------------------------
__global__ void esq_kernel(const float* __restrict__ E, float* __restrict__ e_sq,
                           int* __restrict__ fcount) {
    if (blockIdx.x == 0 && threadIdx.x == 0) *fcount = 0;
    const int wave = threadIdx.x >> 6;
    const int lane = threadIdx.x & 63;
    const int row  = blockIdx.x * 4 + wave;
    const float4* p = reinterpret_cast<const float4*>(E + (size_t)row * DIM) + lane * 2;
    float4 a = p[0], b = p[1];
    float s = a.x * a.x + a.y * a.y + a.z * a.z + a.w * a.w
            + b.x * b.x + b.y * b.y + b.z * b.z + b.w * b.w;
    #pragma unroll
    for (int off = 32; off > 0; off >>= 1) s += __shfl_down(s, off, 64);
    if (lane == 0) e_sq[row] = s;
}

// ---------------------------------------------------------------------------
// Single-MFMA f16 scorer: 128 rows x 512 codes per block, global_load_lds
// staging from packed planes, running per-row (best, second, idx) -> partials.
// ---------------------------------------------------------------------------
__global__ __launch_bounds__(256, 2)
void vq_mfma_kernel(const _Float16* __restrict__ Xp, const _Float16* __restrict__ Ep,
                    const float* __restrict__ e_sq,
                    float* __restrict__ pbest, float* __restrict__ psec,
                    int* __restrict__ pidx)
{
    __shared__ _Float16 As[16 * 512];   // 16 KB: 16 fragment tiles (128 rows x 64 k)
    __shared__ _Float16 Bs[16 * 512];   // 16 KB
    __shared__ float reds1[BM][2], reds2[BM][2];
    __shared__ int   redi [BM][2];

    const int tid  = threadIdx.x;
    const int lane = tid & 63;
    const int w    = tid >> 6;
    const int wr   = w >> 1;          // wave row half (0/1)
    const int wc   = w & 1;           // wave col half (0/1)

    // XCD-aware swizzle over 1024 flat blocks: XCD c owns code-chunks
    // {2c, 2c+1} x all 64 row-blocks -> its 1 MB E-slice stays L2-resident.
    const int bid = blockIdx.x;
    const int xcd = bid & 7, pos = bid >> 3;
    const int cx  = xcd * 2 + (pos >> 6);   // code-chunk 0..15
    const int ry  = pos & 63;               // row-block 0..63
    const int row0  = ry * BM;
    const int cbase = cx * CHUNK;
    const int rtb = row0 >> 4;              // global row-tile base

    float s1[16], s2[16];
    int   i1[16];
    #pragma unroll
    for (int i = 0; i < 16; ++i) { s1[i] = -INFINITY; s2[i] = -INFINITY; i1[i] = 0; }

    for (int nt = 0; nt < NT; ++nt) {
        const int code0 = cbase + nt * BN;
        const int ctb = code0 >> 4;
        f32x4 acc[4][4];
        #pragma unroll
        for (int m = 0; m < 4; ++m)
            #pragma unroll
            for (int n = 0; n < 4; ++n)
                acc[m][n] = (f32x4){0.f, 0.f, 0.f, 0.f};

        for (int kt2 = 0; kt2 < KT; kt2 += 2) {     // 8 steps of BK=64
            // Stage 16 A-tiles + 16 B-tiles (1 KB each); wave w does 4 of each.
            #pragma unroll
            for (int i = 0; i < 4; ++i) {
                const int t   = w * 4 + i;
                const int rt  = t >> 1, ktl = t & 1;
                const size_t ga = ((size_t)(rtb + rt) * KT + kt2 + ktl) * 512 + lane * 8;
                const size_t gb = ((size_t)(ctb + rt) * KT + kt2 + ktl) * 512 + lane * 8;
                __builtin_amdgcn_global_load_lds(
                    (const __attribute__((address_space(1))) void*)(Xp + ga),
                    (__attribute__((address_space(3))) void*)(&As[t * 512]), 16, 0, 0);
                __builtin_amdgcn_global_load_lds(
                    (const __attribute__((address_space(1))) void*)(Ep + gb),
                    (__attribute__((address_space(3))) void*)(&Bs[t * 512]), 16, 0, 0);
            }
            __syncthreads();

            #pragma unroll
            for (int kk = 0; kk < 2; ++kk) {
                f16x8 bfrag[4];
                #pragma unroll
                for (int n = 0; n < 4; ++n)
                    bfrag[n] = *reinterpret_cast<const f16x8*>(
                        &Bs[((wc * 4 + n) * 2 + kk) * 512 + lane * 8]);
                #pragma unroll
                for (int m = 0; m < 4; ++m) {
                    const f16x8 afrag = *reinterpret_cast<const f16x8*>(
                        &As[((wr * 4 + m) * 2 + kk) * 512 + lane * 8]);
                    #pragma unroll
                    for (int n = 0; n < 4; ++n)
                        acc[m][n] = __builtin_amdgcn_mfma_f32_16x16x32_f16(
                            afrag, bfrag[n], acc[m][n], 0, 0, 0);
                }
            }
            __syncthreads();
        }

        // ---- fold this code tile into running (best, second, idx) ----
        #pragma unroll
        for (int n = 0; n < 4; ++n) {
            const int code = code0 + wc * 64 + n * 16 + (lane & 15);
            const float es = e_sq[code];
            #pragma unroll
            for (int m = 0; m < 4; ++m) {
                #pragma unroll
                for (int r = 0; r < 4; ++r) {
                    const float s = fmaf(2.0f, acc[m][n][r], -es);
                    const int slot = m * 4 + r;
                    if (s > s1[slot]) { s2[slot] = s1[slot]; s1[slot] = s; i1[slot] = code; }
                    else if (s > s2[slot]) { s2[slot] = s; }
                    else if (s == s1[slot]) { s2[slot] = s; }   // exact tie -> margin 0
                }
            }
        }
    }

    // ---- cross-lane reduce within each 16-lane col group ----
    #pragma unroll
    for (int slot = 0; slot < 16; ++slot) {
        #pragma unroll
        for (int mask = 1; mask < 16; mask <<= 1) {
            float t1 = __shfl_xor(s1[slot], mask, 64);
            float t2 = __shfl_xor(s2[slot], mask, 64);
            int   j1 = __shfl_xor(i1[slot], mask, 64);
            if (t1 > s1[slot]) { s2[slot] = fmaxf(s1[slot], t2); s1[slot] = t1; i1[slot] = j1; }
            else if (t1 == s1[slot]) { s2[slot] = fmaxf(s2[slot], fmaxf(t1, t2)); i1[slot] = min(i1[slot], j1); }
            else { s2[slot] = fmaxf(s2[slot], t1); }
        }
    }

    if ((lane & 15) == 0) {
        #pragma unroll
        for (int m = 0; m < 4; ++m)
            #pragma unroll
            for (int r = 0; r < 4; ++r) {
                const int row = wr * 64 + m * 16 + (lane >> 4) * 4 + r;
                reds1[row][wc] = s1[m * 4 + r];
                reds2[row][wc] = s2[m * 4 + r];
                redi [row][wc] = i1[m * 4 + r];
            }
    }
    __syncthreads();

    if (tid < BM) {
        float a1 = reds1[tid][0], a2 = reds2[tid][0]; int ai = redi[tid][0];
        const float b1 = reds1[tid][1], b2 = reds2[tid][1]; const int bi = redi[tid][1];
        if (b1 > a1)       { a2 = fmaxf(a1, b2); a1 = b1; ai = bi; }
        else if (b1 == a1) { a2 = fmaxf(a2, fmaxf(b1, b2)); ai = min(ai, bi); }
        else               { a2 = fmaxf(a2, b1); }
        const int row = row0 + tid;
        pbest[(size_t)row * NXB + cx] = a1;
        psec [(size_t)row * NXB + cx] = a2;
        pidx [(size_t)row * NXB + cx] = ai;
    }
}

// ---------------------------------------------------------------------------
// Merge NXB partials per row; compact rows with small margin into frow[].
// ---------------------------------------------------------------------------
__global__ void reduce_kernel(const float* __restrict__ pbest, const float* __restrict__ psec,
                              const int* __restrict__ pidx,
                              int* __restrict__ final_idx,
                              int* __restrict__ fcount, int* __restrict__ frow,
                              int* __restrict__ fslot)
{
    const int row = blockIdx.x * 256 + threadIdx.x;
    float s1 = -INFINITY, s2 = -INFINITY; int i1 = 0;
    #pragma unroll
    for (int j = 0; j < NXB; ++j) {
        const float t1 = pbest[(size_t)row * NXB + j];
        const float t2 = psec [(size_t)row * NXB + j];
        const int   j1 = pidx [(size_t)row * NXB + j];
        if (t1 > s1)       { s2 = fmaxf(s1, t2); s1 = t1; i1 = j1; }
        else if (t1 == s1) { s2 = fmaxf(s2, fmaxf(t1, t2)); i1 = min(i1, j1); }
        else               { s2 = fmaxf(s2, t1); }
    }
    final_idx[row] = i1;
    int slot = -1;
    if (s1 - s2 < EPS) {
        const int f = atomicAdd(fcount, 1);
        if (f < MAXF) { frow[f] = row; slot = f; }
    }
    fslot[row] = slot;
}

// ---------------------------------------------------------------------------
// Exact fp32 rescore, parallel: block (f, chunk) scans 512 codes for one
// flagged row; wave per code-group, lanes split the 512 dims (coalesced).
// ---------------------------------------------------------------------------
__global__ __launch_bounds__(256)
void rescue_kernel(const float* __restrict__ X, const float* __restrict__ E,
                   const float* __restrict__ e_sq,
                   const int* __restrict__ fcount, const int* __restrict__ frow,
                   float* __restrict__ rbest, int* __restrict__ ridx)
{
    const int f = blockIdx.x;
    const int nf = *fcount;
    if (f >= nf || f >= MAXF) return;
    const int row  = frow[f];
    const int lane = threadIdx.x & 63;
    const int w    = threadIdx.x >> 6;

    const float4* xp = reinterpret_cast<const float4*>(X + (size_t)row * DIM) + lane * 2;
    const float4 x0 = xp[0], x1 = xp[1];

    const int c0 = blockIdx.y * RCODES + w * (RCODES / 4);
    float best = -INFINITY; int bi = 0;
    for (int c = c0; c < c0 + RCODES / 4; ++c) {
        const float4* ep = reinterpret_cast<const float4*>(E + (size_t)c * DIM) + lane * 2;
        const float4 e0 = ep[0], e1 = ep[1];
        float dot = x0.x * e0.x;
        dot = fmaf(x0.y, e0.y, dot);
        dot = fmaf(x0.z, e0.z, dot);
        dot = fmaf(x0.w, e0.w, dot);
        dot = fmaf(x1.x, e1.x, dot);
        dot = fmaf(x1.y, e1.y, dot);
        dot = fmaf(x1.z, e1.z, dot);
        dot = fmaf(x1.w, e1.w, dot);
        #pragma unroll
        for (int mask = 1; mask < 64; mask <<= 1) dot += __shfl_xor(dot, mask, 64);
        const float s = fmaf(2.f, dot, -e_sq[c]);
        if (s > best) { best = s; bi = c; }    // ascending c: first occurrence wins
    }
    if (lane == 0) {
        const int p = f * 64 + blockIdx.y * 4 + w;
        rbest[p] = best; ridx[p] = bi;
    }
}

// ---------------------------------------------------------------------------
// Final index (rescued rows merge their 64 partials), write index + gather.
// Fully overwrites d_out (which held the packed fp16 planes until now).
// ---------------------------------------------------------------------------
__global__ void gather_kernel(const int* __restrict__ final_idx,
                              const int* __restrict__ fslot,
                              const float* __restrict__ rbest, const int* __restrict__ ridx,
                              const float* __restrict__ E,
                              float* __restrict__ out_q, float* __restrict__ out_i)
{
    const int row = blockIdx.x;
    __shared__ int s_bi;
    if (threadIdx.x < 64) {
        const int slot = fslot[row];
        int bi;
        if (slot >= 0) {
            float b = rbest[slot * 64 + threadIdx.x];
            bi = ridx[slot * 64 + threadIdx.x];
            #pragma unroll
            for (int mask = 1; mask < 64; mask <<= 1) {
                const float ob = __shfl_xor(b, mask, 64);
                const int   oi = __shfl_xor(bi, mask, 64);
                if (ob > b || (ob == b && oi < bi)) { b = ob; bi = oi; }
            }
        } else {
            bi = final_idx[row];
        }
        if (threadIdx.x == 0) { s_bi = bi; out_i[row] = (float)bi; }
    }
    __syncthreads();
    const int bi = s_bi;
    const float4* src = reinterpret_cast<const float4*>(E + (size_t)bi * DIM);
    float4* dst = reinterpret_cast<float4*>(out_q + (size_t)row * DIM);
    dst[threadIdx.x] = src[threadIdx.x];
}

// ---------------------------------------------------------------------------
extern "C" void kernel_launch(void* const* d_in, const int* in_sizes, int n_in,
                              void* d_out, int out_size, void* d_ws, size_t ws_size,
                              hipStream_t stream) {
    const float* X = (const float*)d_in[0];   // [8192, 512]
    const float* E = (const float*)d_in[1];   // [8192, 512]

    float* out_q = (float*)d_out;                         // [8192, 512]
    float* out_i = (float*)d_out + (size_t)NR * DIM;      // [8192]

    // Packed fp16 planes live in d_out's space (16 MB needed, 16.03 MB there);
    // gather_kernel fully overwrites d_out at the end of every launch.
    _Float16* Xp = (_Float16*)d_out;                      // 8 MB
    _Float16* Ep = Xp + (size_t)NR * DIM;                 // 8 MB

    float* e_sq      = (float*)d_ws;                      // 8192 f
    float* pbest     = e_sq + KC;                         // 8192*16 f
    float* psec      = pbest + (size_t)NR * NXB;          // 8192*16 f
    int*   pidx      = (int*)(psec + (size_t)NR * NXB);   // 8192*16 i
    int*   final_idx = pidx + (size_t)NR * NXB;           // 8192 i
    int*   fcount    = final_idx + NR;                    // 1 i
    int*   frow      = fcount + 1;                        // MAXF i
    int*   fslot     = frow + MAXF;                       // 8192 i
    float* rbest     = (float*)(fslot + NR);              // MAXF*64 f
    int*   ridx      = (int*)(rbest + MAXF * 64);         // MAXF*64 i

    hipLaunchKernelGGL(esq_kernel, dim3(KC / 4), dim3(256), 0, stream, E, e_sq, fcount);

    hipLaunchKernelGGL(pack_kernel, dim3(NR * DIM / (16 * 32) / 4, 2), dim3(256), 0, stream,
                       X, E, Xp, Ep);

    hipLaunchKernelGGL(vq_mfma_kernel, dim3(NXB * (NR / BM)), dim3(256), 0, stream,
                       Xp, Ep, e_sq, pbest, psec, pidx);

    hipLaunchKernelGGL(reduce_kernel, dim3(NR / 256), dim3(256), 0, stream,
                       pbest, psec, pidx, final_idx, fcount, frow, fslot);

    hipLaunchKernelGGL(rescue_kernel, dim3(MAXF, KC / RCODES), dim3(256), 0, stream,
                       X, E, e_sq, fcount, frow, rbest, ridx);

    hipLaunchKernelGGL(gather_kernel, dim3(NR), dim3(128), 0, stream,
                       final_idx, fslot, rbest, ridx, E, out_q, out_i);
}